// Round 1
// baseline (308.634 us; speedup 1.0000x reference)
//
#include <hip/hip_runtime.h>

#define NS 65536      // stocks
#define HID 512       // hidden
#define NE 128        // industries
#define CHUNKS 8      // per-industry chunks in aggregation
#define NEG 0.01f     // LeakyReLU slope

// K1: decode one-hot rows -> ind[s], and histogram counts per industry.
__global__ __launch_bounds__(256) void k_find(const int* __restrict__ im,
                                              int* __restrict__ ind,
                                              int* __restrict__ hist) {
    const int total = NS * (NE / 4);  // int4 elements
    for (int i = blockIdx.x * blockDim.x + threadIdx.x; i < total;
         i += gridDim.x * blockDim.x) {
        int4 v = reinterpret_cast<const int4*>(im)[i];
        int s = i >> 5;           // 32 int4 per row of 128 ints
        int c = (i & 31) * 4;
        if (v.x == 1) { ind[s] = c;     atomicAdd(&hist[c], 1); }
        if (v.y == 1) { ind[s] = c + 1; atomicAdd(&hist[c + 1], 1); }
        if (v.z == 1) { ind[s] = c + 2; atomicAdd(&hist[c + 2], 1); }
        if (v.w == 1) { ind[s] = c + 3; atomicAdd(&hist[c + 3], 1); }
    }
}

// K2: exclusive scan of hist -> off, and Binv = 1/count.
__global__ __launch_bounds__(128) void k_scan(const int* __restrict__ hist,
                                              int* __restrict__ off,
                                              float* __restrict__ binv) {
    int e = threadIdx.x;
    if (e == 0) {
        int acc = 0;
        for (int k = 0; k < NE; ++k) { off[k] = acc; acc += hist[k]; }
    }
    if (e < NE) {
        int b = hist[e];
        binv[e] = (b > 0) ? 1.0f / (float)b : 0.0f;
    }
}

// K3: counting-sort scatter: sorted[] holds stock ids grouped by industry.
__global__ __launch_bounds__(256) void k_scatter(const int* __restrict__ ind,
                                                 const int* __restrict__ off,
                                                 int* __restrict__ cursor,
                                                 int* __restrict__ sorted) {
    int s = blockIdx.x * blockDim.x + threadIdx.x;
    if (s < NS) {
        int e = ind[s];
        int p = atomicAdd(&cursor[e], 1);
        sorted[off[e] + p] = s;
    }
}

// K4: per-industry sum of e_s rows, register-accumulated.
// grid = NE * CHUNKS blocks, 256 threads; thread owns 2 consecutive columns.
__global__ __launch_bounds__(256) void k_aggregate(const float* __restrict__ e_s,
                                                   const int* __restrict__ sorted,
                                                   const int* __restrict__ hist,
                                                   const int* __restrict__ off,
                                                   float* __restrict__ agg) {
    int e = blockIdx.x / CHUNKS;
    int c = blockIdx.x % CHUNKS;
    int len = hist[e];
    int base = off[e];
    int i0 = base + (int)((long long)c * len / CHUNKS);
    int i1 = base + (int)((long long)(c + 1) * len / CHUNKS);
    int t = threadIdx.x;
    float ax = 0.0f, ay = 0.0f;
    for (int i = i0; i < i1; ++i) {
        int row = sorted[i];  // wave-uniform -> scalar load
        float2 v = reinterpret_cast<const float2*>(e_s + (size_t)row * HID)[t];
        ax += v.x;
        ay += v.y;
    }
    atomicAdd(&agg[e * HID + 2 * t],     ax);
    atomicAdd(&agg[e * HID + 2 * t + 1], ay);
}

// K5: edge_feat[e][j] = Binv[e] * sum_k agg[e][k] * W[k][j]
__global__ __launch_bounds__(512) void k_edge_gemm(const float* __restrict__ agg,
                                                   const float* __restrict__ W,
                                                   const float* __restrict__ binv,
                                                   float* __restrict__ ef) {
    __shared__ float a[HID];
    int e = blockIdx.x;
    int j = threadIdx.x;
    a[j] = agg[e * HID + j];
    __syncthreads();
    float acc = 0.0f;
#pragma unroll 8
    for (int k = 0; k < HID; ++k) {
        acc += a[k] * W[k * HID + j];  // a[k]: LDS broadcast; W: coalesced
    }
    ef[e * HID + j] = acc * binv[e];
}

// K6: out[s][:] = LeakyReLU(edge_feat[ind[s]][:] + bias)
__global__ __launch_bounds__(256) void k_out(const float* __restrict__ ef,
                                             const int* __restrict__ ind,
                                             const float* __restrict__ bias,
                                             float* __restrict__ out) {
    const int total = NS * (HID / 4);  // float4 elements
    for (int i = blockIdx.x * blockDim.x + threadIdx.x; i < total;
         i += gridDim.x * blockDim.x) {
        int s = i >> 7;          // 128 float4 per row
        int c4 = i & 127;
        int e = ind[s];
        float4 v = reinterpret_cast<const float4*>(ef + (size_t)e * HID)[c4];
        float4 b = reinterpret_cast<const float4*>(bias)[c4];
        v.x += b.x; v.y += b.y; v.z += b.z; v.w += b.w;
        v.x = (v.x >= 0.0f) ? v.x : NEG * v.x;
        v.y = (v.y >= 0.0f) ? v.y : NEG * v.y;
        v.z = (v.z >= 0.0f) ? v.z : NEG * v.z;
        v.w = (v.w >= 0.0f) ? v.w : NEG * v.w;
        reinterpret_cast<float4*>(out)[i] = v;
    }
}

extern "C" void kernel_launch(void* const* d_in, const int* in_sizes, int n_in,
                              void* d_out, int out_size, void* d_ws, size_t ws_size,
                              hipStream_t stream) {
    const float* e_s  = (const float*)d_in[0];
    const int*   im   = (const int*)d_in[1];
    const float* W    = (const float*)d_in[2];
    const float* bias = (const float*)d_in[3];
    float* out = (float*)d_out;

    char* ws = (char*)d_ws;
    // layout (bytes):
    int*   ind    = (int*)(ws + 0);            // 262144
    int*   sorted = (int*)(ws + 262144);       // 262144
    float* agg    = (float*)(ws + 524288);     // 262144
    float* ef     = (float*)(ws + 786432);     // 262144
    int*   hist   = (int*)(ws + 1048576);      // 512
    int*   cursor = (int*)(ws + 1049088);      // 512
    int*   off    = (int*)(ws + 1049600);      // 512
    float* binv   = (float*)(ws + 1050112);    // 512

    // zero the accumulators (hist+cursor contiguous 1 KB, agg 256 KB)
    hipMemsetAsync(ws + 1048576, 0, 1024, stream);
    hipMemsetAsync(ws + 524288, 0, 262144, stream);

    k_find<<<2048, 256, 0, stream>>>(im, ind, hist);
    k_scan<<<1, 128, 0, stream>>>(hist, off, binv);
    k_scatter<<<NS / 256, 256, 0, stream>>>(ind, off, cursor, sorted);
    k_aggregate<<<NE * CHUNKS, 256, 0, stream>>>(e_s, sorted, hist, off, agg);
    k_edge_gemm<<<NE, 512, 0, stream>>>(agg, W, binv, ef);
    k_out<<<4096, 256, 0, stream>>>(ef, ind, bias, out);
}

// Round 2
// 113.381 us; speedup vs baseline: 2.7221x; 2.7221x over previous
//
#include <hip/hip_runtime.h>

#define NS 65536      // stocks
#define HID 512       // hidden
#define NE 128        // industries
#define NB 256        // blocks in find/scatter (256 stocks each)
#define PC 2          // partial chunks per industry in aggregation
#define NEG 0.01f     // LeakyReLU slope

// ---------------------------------------------------------------------------
// K1: decode one-hot rows -> ind[s]; per-block LDS histogram -> blockHist.
// Block b owns stocks [b*256, b*256+256). Reads its 128 KB chunk coalesced.
// NO global atomics.
__global__ __launch_bounds__(256) void k_find(const int* __restrict__ im,
                                              int* __restrict__ ind,
                                              int* __restrict__ bhist) {
    __shared__ int lind[256];
    __shared__ int lhist[NE];
    const int b = blockIdx.x, t = threadIdx.x;
    if (t < NE) lhist[t] = 0;
    const int4* p = reinterpret_cast<const int4*>(im) + (size_t)b * 8192;
    for (int j = t; j < 8192; j += 256) {   // 256 rows x 32 int4
        int4 v = p[j];
        int s = j >> 5;          // local row
        int c = (j & 31) << 2;   // column of v.x
        if (v.x == 1) lind[s] = c;
        if (v.y == 1) lind[s] = c + 1;
        if (v.z == 1) lind[s] = c + 2;
        if (v.w == 1) lind[s] = c + 3;
    }
    __syncthreads();
    int e = lind[t];
    ind[b * 256 + t] = e;
    atomicAdd(&lhist[e], 1);     // LDS atomic only
    __syncthreads();
    if (t < NE) bhist[b * NE + t] = lhist[t];
}

// ---------------------------------------------------------------------------
// K2: single block. totals -> off (exclusive scan, 129 entries), binv,
// and per-block scatter bases baseArr[b][e].
__global__ __launch_bounds__(128) void k_scan(const int* __restrict__ bhist,
                                              int* __restrict__ off,
                                              float* __restrict__ binv,
                                              int* __restrict__ baseArr) {
    __shared__ int tot[NE];
    __shared__ int offs[NE + 1];
    const int e = threadIdx.x;
    int s = 0;
    for (int b = 0; b < NB; ++b) s += bhist[b * NE + e];  // coalesced across e
    tot[e] = s;
    __syncthreads();
    if (e == 0) {
        int a = 0;
        for (int k = 0; k < NE; ++k) { offs[k] = a; a += tot[k]; }
        offs[NE] = a;
    }
    __syncthreads();
    off[e] = offs[e];
    if (e == 0) off[NE] = offs[NE];
    binv[e] = (tot[e] > 0) ? 1.0f / (float)tot[e] : 0.0f;
    int p = offs[e];
    for (int b = 0; b < NB; ++b) {
        baseArr[b * NE + e] = p;
        p += bhist[b * NE + e];
    }
}

// ---------------------------------------------------------------------------
// K3: scatter stock ids grouped by industry. LDS atomics only.
__global__ __launch_bounds__(256) void k_scatter(const int* __restrict__ ind,
                                                 const int* __restrict__ baseArr,
                                                 int* __restrict__ sorted) {
    __shared__ int cnt[NE];
    const int b = blockIdx.x, t = threadIdx.x;
    if (t < NE) cnt[t] = 0;
    __syncthreads();
    int e = ind[b * 256 + t];
    int p = atomicAdd(&cnt[e], 1);   // LDS atomic
    sorted[baseArr[b * NE + e] + p] = b * 256 + t;
}

// ---------------------------------------------------------------------------
// K4: per-industry row-sum of e_s. Grid = NE*PC blocks x 512 threads (8 waves).
// Group g = t>>7 (4 groups) sums rows i0+g, i0+g+4, ...; lane l = t&127 owns
// float4 columns 4l..4l+3. Row ids staged in LDS. Writes disjoint
// partial[c][e][:]. NO atomics at all.
__global__ __launch_bounds__(512) void k_aggregate(const float* __restrict__ e_s,
                                                   const int* __restrict__ sorted,
                                                   const int* __restrict__ off,
                                                   float* __restrict__ partial) {
    __shared__ int rows[1024];
    __shared__ float4 red[512];
    const int e = blockIdx.x >> 1;
    const int c = blockIdx.x & 1;
    const int t = threadIdx.x;
    const int s0 = off[e], s1 = off[e + 1];
    const int len = s1 - s0;
    const int i0 = s0 + (c * len) / PC;
    const int i1 = s0 + ((c + 1) * len) / PC;
    const int seg = i1 - i0;
    const int stage = (seg < 1024) ? seg : 1024;
    for (int k = t; k < stage; k += 512) rows[k] = sorted[i0 + k];
    __syncthreads();
    const int g = t >> 7;        // wave-uniform
    const int l = t & 127;
    float4 acc = {0.f, 0.f, 0.f, 0.f};
#pragma unroll 4
    for (int i = i0 + g; i < i1; i += 4) {
        int idx = i - i0;
        int row = (idx < stage) ? rows[idx] : sorted[i];   // uniform broadcast
        float4 v = reinterpret_cast<const float4*>(e_s + (size_t)row * HID)[l];
        acc.x += v.x; acc.y += v.y; acc.z += v.z; acc.w += v.w;
    }
    red[t] = acc;
    __syncthreads();
    if (g == 0) {
        float4 a = red[t], b2 = red[t + 128], c2 = red[t + 256], d2 = red[t + 384];
        a.x += b2.x + c2.x + d2.x;
        a.y += b2.y + c2.y + d2.y;
        a.z += b2.z + c2.z + d2.z;
        a.w += b2.w + c2.w + d2.w;
        reinterpret_cast<float4*>(partial + ((size_t)c * NE + e) * HID)[l] = a;
    }
}

// ---------------------------------------------------------------------------
// K5: edge_feat[e][j] = Binv[e] * sum_k (partial0+partial1)[e][k] * W[k][j]
__global__ __launch_bounds__(512) void k_edge_gemm(const float* __restrict__ partial,
                                                   const float* __restrict__ W,
                                                   const float* __restrict__ binv,
                                                   float* __restrict__ ef) {
    __shared__ float a[HID];
    const int e = blockIdx.x;
    const int j = threadIdx.x;
    a[j] = partial[(size_t)e * HID + j] + partial[((size_t)NE + e) * HID + j];
    __syncthreads();
    float acc = 0.0f;
#pragma unroll 8
    for (int k = 0; k < HID; ++k) {
        acc += a[k] * W[k * HID + j];   // a[k]: LDS broadcast; W: coalesced
    }
    ef[(size_t)e * HID + j] = acc * binv[e];
}

// ---------------------------------------------------------------------------
// K6: out[s][:] = LeakyReLU(edge_feat[ind[s]][:] + bias)
__global__ __launch_bounds__(256) void k_out(const float* __restrict__ ef,
                                             const int* __restrict__ ind,
                                             const float* __restrict__ bias,
                                             float* __restrict__ out) {
    const int total = NS * (HID / 4);  // float4 elements
    for (int i = blockIdx.x * blockDim.x + threadIdx.x; i < total;
         i += gridDim.x * blockDim.x) {
        int s = i >> 7;          // 128 float4 per row
        int c4 = i & 127;
        int e = ind[s];
        float4 v = reinterpret_cast<const float4*>(ef + (size_t)e * HID)[c4];
        float4 b = reinterpret_cast<const float4*>(bias)[c4];
        v.x += b.x; v.y += b.y; v.z += b.z; v.w += b.w;
        v.x = (v.x >= 0.0f) ? v.x : NEG * v.x;
        v.y = (v.y >= 0.0f) ? v.y : NEG * v.y;
        v.z = (v.z >= 0.0f) ? v.z : NEG * v.z;
        v.w = (v.w >= 0.0f) ? v.w : NEG * v.w;
        reinterpret_cast<float4*>(out)[i] = v;
    }
}

extern "C" void kernel_launch(void* const* d_in, const int* in_sizes, int n_in,
                              void* d_out, int out_size, void* d_ws, size_t ws_size,
                              hipStream_t stream) {
    const float* e_s  = (const float*)d_in[0];
    const int*   im   = (const int*)d_in[1];
    const float* W    = (const float*)d_in[2];
    const float* bias = (const float*)d_in[3];
    float* out = (float*)d_out;

    char* ws = (char*)d_ws;
    // Aliased layout (lifetimes disjoint), total 1,050,112 B:
    //   [0,       256K) ind      (K1 -> K6)
    //   [256K,    512K) sorted   (K3 -> K4), then ef (K5 -> K6)
    //   [512K,    640K) blockHist(K1 -> K2) }  overlaid by
    //   [640K,    768K) baseArr  (K2 -> K3) }  partial[2][128][512] (K4 -> K5)
    //   [512K,   1024K) partial
    //   [1024K, +516B ) off[129]
    //   [1024K+1K,+512B) binv[128]
    int*   ind     = (int*)(ws + 0);
    int*   sorted  = (int*)(ws + 262144);
    float* ef      = (float*)(ws + 262144);
    int*   bhist   = (int*)(ws + 524288);
    int*   baseArr = (int*)(ws + 655360);
    float* partial = (float*)(ws + 524288);
    int*   off     = (int*)(ws + 1048576);
    float* binv    = (float*)(ws + 1049600);

    k_find     <<<NB, 256, 0, stream>>>(im, ind, bhist);
    k_scan     <<<1, 128, 0, stream>>>(bhist, off, binv, baseArr);
    k_scatter  <<<NB, 256, 0, stream>>>(ind, baseArr, sorted);
    k_aggregate<<<NE * PC, 512, 0, stream>>>(e_s, sorted, off, partial);
    k_edge_gemm<<<NE, 512, 0, stream>>>(partial, W, binv, ef);
    k_out      <<<4096, 256, 0, stream>>>(ef, ind, bias, out);
}

// Round 5
// 108.531 us; speedup vs baseline: 2.8438x; 1.0447x over previous
//
#include <hip/hip_runtime.h>

#define NS 65536      // stocks
#define HID 512       // hidden
#define NE 128        // industries
#define NB 256        // blocks in find/scatter (256 stocks each)
#define PC 2          // partial chunks per industry in aggregation
#define NEG 0.01f     // LeakyReLU slope

// ---------------------------------------------------------------------------
// K1: decode one-hot rows -> ind[s]; per-block LDS histogram -> bhist.
// Block b owns stocks [b*256, b*256+256). No global atomics.
__global__ __launch_bounds__(256) void k_find(const int* __restrict__ im,
                                              int* __restrict__ ind,
                                              int* __restrict__ bhist) {
    __shared__ int lind[256];
    __shared__ int lhist[NE];
    const int b = blockIdx.x, t = threadIdx.x;
    if (t < NE) lhist[t] = 0;
    const int4* p = reinterpret_cast<const int4*>(im) + (size_t)b * 8192;
#pragma unroll
    for (int j = t; j < 8192; j += 256) {   // 256 rows x 32 int4
        int4 v = p[j];
        int s = j >> 5;          // local row
        int c = (j & 31) << 2;   // column of v.x
        if (v.x == 1) lind[s] = c;
        if (v.y == 1) lind[s] = c + 1;
        if (v.z == 1) lind[s] = c + 2;
        if (v.w == 1) lind[s] = c + 3;
    }
    __syncthreads();
    int e = lind[t];
    ind[b * 256 + t] = e;
    atomicAdd(&lhist[e], 1);     // LDS atomic only
    __syncthreads();
    if (t < NE) bhist[b * NE + t] = lhist[t];
}

// ---------------------------------------------------------------------------
// K2: scatter with inlined scan. Every block recomputes the global prefix
// from bhist (L2-resident, ~1us aggregate); block 0 publishes off[129]+binv.
// LDS atomics only.
__global__ __launch_bounds__(256) void k_scatter(const int* __restrict__ ind,
                                                 const int* __restrict__ bhist,
                                                 int* __restrict__ sorted,
                                                 int* __restrict__ off,
                                                 float* __restrict__ binv) {
    __shared__ int totL[NE];
    __shared__ int offL[NE + 1];
    __shared__ int baseL[NE];
    __shared__ int cnt[NE];
    const int b = blockIdx.x, t = threadIdx.x;
    if (t < NE) {
        int base = 0, tot = 0;
#pragma unroll 8
        for (int b2 = 0; b2 < NB; ++b2) {
            int v = bhist[b2 * NE + t];   // coalesced 512B per b2
            if (b2 < b) base += v;
            tot += v;
        }
        totL[t] = tot;
        baseL[t] = base;
        cnt[t] = 0;
    }
    __syncthreads();
    if (t == 0) {
        int a = 0;
        for (int k = 0; k < NE; ++k) { offL[k] = a; a += totL[k]; }
        offL[NE] = a;
    }
    __syncthreads();
    if (t < NE) baseL[t] += offL[t];
    if (b == 0) {
        if (t < NE) {
            off[t] = offL[t];
            binv[t] = (totL[t] > 0) ? 1.0f / (float)totL[t] : 0.0f;
        }
        if (t == 0) off[NE] = offL[NE];
    }
    __syncthreads();
    int e = ind[b * 256 + t];
    int p = atomicAdd(&cnt[e], 1);   // LDS atomic
    sorted[baseL[e] + p] = b * 256 + t;
}

// ---------------------------------------------------------------------------
// K3: per-industry row-sum of e_s. Grid = NE*PC blocks x 1024 threads
// (16 waves/CU). Group g = t>>7 (8 groups) sums rows i0+g, i0+g+8, ...;
// lane l = t&127 owns float4 columns 4l..4l+3. Row ids staged in LDS.
// Writes disjoint partial[c][e][:]. No atomics.
__global__ __launch_bounds__(1024) void k_aggregate(const float* __restrict__ e_s,
                                                    const int* __restrict__ sorted,
                                                    const int* __restrict__ off,
                                                    float* __restrict__ partial) {
    __shared__ int rows[512];
    __shared__ float4 red[1024];
    const int e = blockIdx.x >> 1;
    const int c = blockIdx.x & 1;
    const int t = threadIdx.x;
    const int s0 = off[e], s1 = off[e + 1];
    const int len = s1 - s0;
    const int i0 = s0 + (c * len) / PC;
    const int i1 = s0 + ((c + 1) * len) / PC;
    const int seg = i1 - i0;
    const int stage = (seg < 512) ? seg : 512;  // expected ~256, guard anyway
    for (int k = t; k < stage; k += 1024) rows[k] = sorted[i0 + k];
    __syncthreads();
    const int g = t >> 7;        // wave-uniform
    const int l = t & 127;
    float4 acc = {0.f, 0.f, 0.f, 0.f};
#pragma unroll 2
    for (int i = i0 + g; i < i1; i += 8) {
        int idx = i - i0;
        int row = (idx < stage) ? rows[idx] : sorted[i];   // uniform broadcast
        float4 v = reinterpret_cast<const float4*>(e_s + (size_t)row * HID)[l];
        acc.x += v.x; acc.y += v.y; acc.z += v.z; acc.w += v.w;
    }
    red[t] = acc;
    __syncthreads();
    if (g == 0) {
        float4 a = red[l];
#pragma unroll
        for (int q = 1; q < 8; ++q) {
            float4 o = red[l + q * 128];
            a.x += o.x; a.y += o.y; a.z += o.z; a.w += o.w;
        }
        reinterpret_cast<float4*>(partial + ((size_t)c * NE + e) * HID)[l] = a;
    }
}

// ---------------------------------------------------------------------------
// K4: edge_feat[e][j] = Binv[e] * sum_k (partial0+partial1)[e][k] * W[k][j]
__global__ __launch_bounds__(512) void k_edge_gemm(const float* __restrict__ partial,
                                                   const float* __restrict__ W,
                                                   const float* __restrict__ binv,
                                                   float* __restrict__ ef) {
    __shared__ float a[HID];
    const int e = blockIdx.x;
    const int j = threadIdx.x;
    a[j] = partial[(size_t)e * HID + j] + partial[((size_t)NE + e) * HID + j];
    __syncthreads();
    float acc = 0.0f;
#pragma unroll 8
    for (int k = 0; k < HID; ++k) {
        acc += a[k] * W[k * HID + j];   // a[k]: LDS broadcast; W: coalesced
    }
    ef[(size_t)e * HID + j] = acc * binv[e];
}

// ---------------------------------------------------------------------------
// K5: out[s][:] = LeakyReLU(edge_feat[ind[s]][:] + bias)
__global__ __launch_bounds__(256) void k_out(const float* __restrict__ ef,
                                             const int* __restrict__ ind,
                                             const float* __restrict__ bias,
                                             float* __restrict__ out) {
    const int total = NS * (HID / 4);  // float4 elements
    for (int i = blockIdx.x * blockDim.x + threadIdx.x; i < total;
         i += gridDim.x * blockDim.x) {
        int s = i >> 7;          // 128 float4 per row; wave-uniform
        int c4 = i & 127;
        int e = ind[s];
        float4 v = reinterpret_cast<const float4*>(ef + (size_t)e * HID)[c4];
        float4 b = reinterpret_cast<const float4*>(bias)[c4];
        v.x += b.x; v.y += b.y; v.z += b.z; v.w += b.w;
        v.x = (v.x >= 0.0f) ? v.x : NEG * v.x;
        v.y = (v.y >= 0.0f) ? v.y : NEG * v.y;
        v.z = (v.z >= 0.0f) ? v.z : NEG * v.z;
        v.w = (v.w >= 0.0f) ? v.w : NEG * v.w;
        reinterpret_cast<float4*>(out)[i] = v;
    }
}

extern "C" void kernel_launch(void* const* d_in, const int* in_sizes, int n_in,
                              void* d_out, int out_size, void* d_ws, size_t ws_size,
                              hipStream_t stream) {
    const float* e_s  = (const float*)d_in[0];
    const int*   im   = (const int*)d_in[1];
    const float* W    = (const float*)d_in[2];
    const float* bias = (const float*)d_in[3];
    float* out = (float*)d_out;

    char* ws = (char*)d_ws;
    // Aliased layout (lifetimes disjoint), total 1,050,112 B:
    //   [0,       256K) ind      (K1 -> K5)
    //   [256K,    512K) sorted   (K2 -> K3), then ef (K4 -> K5)
    //   [512K,    640K) bhist    (K1 -> K2) } overlaid by
    //   [512K,   1024K) partial  (K3 -> K4) } (bhist dead before K3 writes)
    //   [1024K, +516B ) off[129]
    //   [1025K, +512B ) binv[128]
    int*   ind     = (int*)(ws + 0);
    int*   sorted  = (int*)(ws + 262144);
    float* ef      = (float*)(ws + 262144);
    int*   bhist   = (int*)(ws + 524288);
    float* partial = (float*)(ws + 524288);
    int*   off     = (int*)(ws + 1048576);
    float* binv    = (float*)(ws + 1049600);

    k_find     <<<NB, 256, 0, stream>>>(im, ind, bhist);
    k_scatter  <<<NB, 256, 0, stream>>>(ind, bhist, sorted, off, binv);
    k_aggregate<<<NE * PC, 1024, 0, stream>>>(e_s, sorted, off, partial);
    k_edge_gemm<<<NE, 512, 0, stream>>>(partial, W, binv, ef);
    k_out      <<<4096, 256, 0, stream>>>(ef, ind, bias, out);
}